// Round 10
// baseline (1220.356 us; speedup 1.0000x reference)
//
#include <hip/hip_runtime.h>

#define BB 8
#define TT 2048
#define EE 768
#define DD 128
#define QROWS 8
#define SCALE 0.08838834764831845f   // 1/sqrt(128)

__device__ __forceinline__ float bf2f(unsigned short u) {
    union { unsigned int i; float f; } c; c.i = ((unsigned int)u) << 16; return c.f;
}
__device__ __forceinline__ unsigned short f2bf(float f) {
    union { float f; unsigned int i; } c; c.f = f;
    unsigned int u = c.i;
    if ((u & 0x7fffffffu) > 0x7f800000u) return (unsigned short)((u >> 16) | 0x0040u);
    u += 0x7fffu + ((u >> 16) & 1u);
    return (unsigned short)(u >> 16);
}
__device__ __forceinline__ void unpack2(unsigned int w, float& lo, float& hi) {
    union { unsigned int i; float f; } a, b;
    a.i = w << 16; b.i = w & 0xffff0000u;
    lo = a.f; hi = b.f;
}

// ---------------- Kernel 1: QKV projection (fp32 in, bf16 ws out) ----------------
// Dict order, row-major W[e*128+d]. Thread d owns column d for 8 rows.
__global__ __launch_bounds__(128) void qkv_naive(
    const float* __restrict__ x,
    const float* __restrict__ Wq, const float* __restrict__ bq,
    const float* __restrict__ Wk, const float* __restrict__ bk,
    const float* __restrict__ Wv, const float* __restrict__ bv,
    unsigned short* __restrict__ Q, unsigned short* __restrict__ K,
    unsigned short* __restrict__ V)
{
    const int r0 = blockIdx.x * QROWS;
    const int d  = threadIdx.x;

    float aq[QROWS], ak[QROWS], av[QROWS];
#pragma unroll
    for (int r = 0; r < QROWS; ++r) { aq[r] = 0.f; ak[r] = 0.f; av[r] = 0.f; }

    for (int e = 0; e < EE; ++e) {
        const float wq = Wq[(size_t)e * DD + d];
        const float wk = Wk[(size_t)e * DD + d];
        const float wv = Wv[(size_t)e * DD + d];
#pragma unroll
        for (int r = 0; r < QROWS; ++r) {
            const float xv = x[(size_t)(r0 + r) * EE + e];
            aq[r] = fmaf(xv, wq, aq[r]);
            ak[r] = fmaf(xv, wk, ak[r]);
            av[r] = fmaf(xv, wv, av[r]);
        }
    }
    const float vbq = bq[d], vbk = bk[d], vbv = bv[d];
#pragma unroll
    for (int r = 0; r < QROWS; ++r) {
        const size_t o = (size_t)(r0 + r) * DD + d;
        Q[o] = f2bf(aq[r] + vbq);
        K[o] = f2bf(ak[r] + vbk);
        V[o] = f2bf(av[r] + vbv);
    }
}

// ---------------- Kernel 2: causal attention, one block per query row ----------------
// OUTPUT IS FLOAT32 — the root-cause fix.
__global__ __launch_bounds__(256) void attn_naive(
    const unsigned short* __restrict__ Q,
    const unsigned short* __restrict__ K,
    const unsigned short* __restrict__ V,
    float* __restrict__ out)
{
    __shared__ float qs[DD];
    __shared__ float sc[TT];
    __shared__ float red[256];

    const int row = blockIdx.x;
    const int b   = row / TT;
    const int qi  = row % TT;
    const int t   = threadIdx.x;

    if (t < DD) qs[t] = bf2f(Q[(size_t)row * DD + t]);
    __syncthreads();

    const unsigned short* Kb = K + (size_t)b * TT * DD;
    float lmax = -1e30f;
    for (int j = t; j <= qi; j += 256) {
        const uint4* kr = (const uint4*)(Kb + (size_t)j * DD);
        float s = 0.f;
#pragma unroll
        for (int e8 = 0; e8 < DD / 8; ++e8) {
            uint4 w = kr[e8];
            float a0, a1;
            unpack2(w.x, a0, a1); s = fmaf(qs[e8*8+0], a0, s); s = fmaf(qs[e8*8+1], a1, s);
            unpack2(w.y, a0, a1); s = fmaf(qs[e8*8+2], a0, s); s = fmaf(qs[e8*8+3], a1, s);
            unpack2(w.z, a0, a1); s = fmaf(qs[e8*8+4], a0, s); s = fmaf(qs[e8*8+5], a1, s);
            unpack2(w.w, a0, a1); s = fmaf(qs[e8*8+6], a0, s); s = fmaf(qs[e8*8+7], a1, s);
        }
        s *= SCALE;
        sc[j] = s;
        lmax = fmaxf(lmax, s);
    }

    red[t] = lmax;
    __syncthreads();
    for (int s = 128; s > 0; s >>= 1) {
        if (t < s) red[t] = fmaxf(red[t], red[t + s]);
        __syncthreads();
    }
    const float m = red[0];
    __syncthreads();

    float lsum = 0.f;
    for (int j = t; j <= qi; j += 256) {
        const float p = __expf(sc[j] - m);
        sc[j] = p;
        lsum += p;
    }
    red[t] = lsum;
    __syncthreads();
    for (int s = 128; s > 0; s >>= 1) {
        if (t < s) red[t] += red[t + s];
        __syncthreads();
    }
    const float invsum = 1.0f / red[0];

    if (t < DD) {
        const unsigned short* Vb = V + (size_t)b * TT * DD;
        float acc = 0.f;
        for (int j = 0; j <= qi; ++j)
            acc = fmaf(sc[j], bf2f(Vb[(size_t)j * DD + t]), acc);
        out[(size_t)row * DD + t] = acc * invsum;   // fp32 store
    }
}

extern "C" void kernel_launch(void* const* d_in, const int* in_sizes, int n_in,
                              void* d_out, int out_size, void* d_ws, size_t ws_size,
                              hipStream_t stream) {
    // Documented dict order: x, Wq, bq, Wk, bk, Wv, bv — all float32.
    const float* x  = (const float*)d_in[0];
    const float* Wq = (const float*)d_in[1];
    const float* bq = (const float*)d_in[2];
    const float* Wk = (const float*)d_in[3];
    const float* bk = (const float*)d_in[4];
    const float* Wv = (const float*)d_in[5];
    const float* bv = (const float*)d_in[6];

    unsigned short* Q = (unsigned short*)d_ws;          // bf16 Q/K/V workspace
    unsigned short* K = Q + (size_t)BB * TT * DD;
    unsigned short* V = K + (size_t)BB * TT * DD;       // 12.58 MB total

    qkv_naive<<<dim3(BB * TT / QROWS), dim3(128), 0, stream>>>(
        x, Wq, bq, Wk, bk, Wv, bv, Q, K, V);

    attn_naive<<<dim3(BB * TT), dim3(256), 0, stream>>>(
        Q, K, V, (float*)d_out);
}

// Round 11
// 321.073 us; speedup vs baseline: 3.8009x; 3.8009x over previous
//
#include <hip/hip_runtime.h>

#define B_ 8
#define T_ 2048
#define E_ 768
#define D_ 128
#define SCALE 0.08838834764831845f   // 1/sqrt(128)

typedef _Float16 h8 __attribute__((ext_vector_type(8)));
typedef _Float16 h4 __attribute__((ext_vector_type(4)));
typedef float f4 __attribute__((ext_vector_type(4)));

// =============== Kernel 1: QKV projection via MFMA ===============
// grid = (128 m-tiles, 3 weights), block = 256 (4 waves, 64x64 quadrants each).
// C[m][n] = x[m][:] . W[:][n] + bias[n]; outputs f16: Q,K row-major, V transposed.
__global__ __launch_bounds__(256) void qkv_mfma(
    const float* __restrict__ x,
    const float* __restrict__ Wq, const float* __restrict__ bq,
    const float* __restrict__ Wk, const float* __restrict__ bk,
    const float* __restrict__ Wv, const float* __restrict__ bv,
    _Float16* __restrict__ Qh, _Float16* __restrict__ Kh,
    _Float16* __restrict__ Vt)
{
    __shared__ _Float16 As[128 * 64];   // x tile, XOR-swizzled 8-half chunks
    __shared__ _Float16 Bs[128 * 64];   // W tile transposed [n][k], same swizzle

    const int t = threadIdx.x;
    const int lane = t & 63, w = t >> 6;
    const int quad = lane >> 4, col = lane & 15;
    const int mhalf = w & 1, nhalf = w >> 1;
    const int m0 = blockIdx.x * 128;
    const int y = blockIdx.y;
    const float* W    = (y == 0) ? Wq : (y == 1) ? Wk : Wv;
    const float* bias = (y == 0) ? bq : (y == 1) ? bk : bv;

    f4 acc[4][4];
#pragma unroll
    for (int mt = 0; mt < 4; ++mt)
#pragma unroll
        for (int nt = 0; nt < 4; ++nt)
            acc[mt][nt] = (f4){0.f, 0.f, 0.f, 0.f};

    for (int kb = 0; kb < E_; kb += 64) {
        // ---- stage x tile (128x64 fp32 -> f16, swizzled) ----
        {
            const int kk4 = (t & 15) * 4, mm0 = t >> 4;
            const int chunk = kk4 >> 3, off = kk4 & 7;
#pragma unroll
            for (int i = 0; i < 8; ++i) {
                const int row = mm0 + 16 * i;
                const float4 v = *(const float4*)&x[(size_t)(m0 + row) * E_ + kb + kk4];
                h4 hv; hv[0] = (_Float16)v.x; hv[1] = (_Float16)v.y;
                hv[2] = (_Float16)v.z; hv[3] = (_Float16)v.w;
                *(h4*)&As[row * 64 + ((chunk ^ (row & 7)) << 3) + off] = hv;
            }
        }
        // ---- stage W tile transposed (64x128 fp32 -> Bs[n][k] f16, swizzled) ----
        {
            const int n4 = (t & 31) * 4, kk0 = t >> 5;
#pragma unroll
            for (int i = 0; i < 8; ++i) {
                const int kk = kk0 + 8 * i;
                const float4 v = *(const float4*)&W[(size_t)(kb + kk) * D_ + n4];
                const int cs = kk >> 3, ko = kk & 7;
                Bs[(n4 + 0) * 64 + ((cs ^ ((n4 + 0) & 7)) << 3) + ko] = (_Float16)v.x;
                Bs[(n4 + 1) * 64 + ((cs ^ ((n4 + 1) & 7)) << 3) + ko] = (_Float16)v.y;
                Bs[(n4 + 2) * 64 + ((cs ^ ((n4 + 2) & 7)) << 3) + ko] = (_Float16)v.z;
                Bs[(n4 + 3) * 64 + ((cs ^ ((n4 + 3) & 7)) << 3) + ko] = (_Float16)v.w;
            }
        }
        __syncthreads();

#pragma unroll
        for (int ks = 0; ks < 2; ++ks) {
            const int sc = ((ks << 2) + quad) ^ (col & 7);
            h8 a[4], b[4];
#pragma unroll
            for (int mt = 0; mt < 4; ++mt)
                a[mt] = *(const h8*)&As[(mhalf * 64 + mt * 16 + col) * 64 + (sc << 3)];
#pragma unroll
            for (int nt = 0; nt < 4; ++nt)
                b[nt] = *(const h8*)&Bs[(nhalf * 64 + nt * 16 + col) * 64 + (sc << 3)];
#pragma unroll
            for (int mt = 0; mt < 4; ++mt)
#pragma unroll
                for (int nt = 0; nt < 4; ++nt)
                    acc[mt][nt] = __builtin_amdgcn_mfma_f32_16x16x32_f16(
                        a[mt], b[nt], acc[mt][nt], 0, 0, 0);
        }
        __syncthreads();
    }

    // ---- epilogue: bias add, store (D layout: row=quad*4+reg, col=lane&15) ----
    float bb[4];
#pragma unroll
    for (int nt = 0; nt < 4; ++nt) bb[nt] = bias[nhalf * 64 + nt * 16 + col];

#pragma unroll
    for (int mt = 0; mt < 4; ++mt) {
        const int mrow = m0 + mhalf * 64 + mt * 16 + quad * 4;
#pragma unroll
        for (int nt = 0; nt < 4; ++nt) {
            const int n = nhalf * 64 + nt * 16 + col;
#pragma unroll
            for (int reg = 0; reg < 4; ++reg) {
                const float val = acc[mt][nt][reg] + bb[nt];
                const int m = mrow + reg;
                if (y == 2) {
                    const int batch = m >> 11, tt = m & 2047;
                    Vt[((size_t)batch * D_ + n) * T_ + tt] = (_Float16)val;
                } else {
                    _Float16* O = (y == 0) ? Qh : Kh;
                    O[(size_t)m * D_ + n] = (_Float16)val;
                }
            }
        }
    }
}

// =============== Kernel 2: flash attention via MFMA ===============
// grid = (T/64, B), block = 256 (4 waves x 16 query rows). K-tiles of 64.
__global__ __launch_bounds__(256) void flash_attn(
    const _Float16* __restrict__ Qh,
    const _Float16* __restrict__ Kh,
    const _Float16* __restrict__ Vt,
    float* __restrict__ out)
{
    __shared__ _Float16 Pl[4][16][72];   // per-wave P scratch (C-layout -> A-layout)

    const int t = threadIdx.x, lane = t & 63, w = t >> 6;
    const int quad = lane >> 4, col = lane & 15;
    const int qbase = blockIdx.x * 64;
    const int b = blockIdx.y;
    const int qrow = qbase + w * 16;

    // Q fragments (A-layout: m=lane&15, k=quad*8+j), resident for whole kernel
    h8 qf[4];
    const _Float16* Qp = Qh + ((size_t)b * T_ + qrow + col) * D_ + quad * 8;
#pragma unroll
    for (int ks = 0; ks < 4; ++ks) qf[ks] = *(const h8*)(Qp + ks * 32);

    f4 o[8];
#pragma unroll
    for (int i = 0; i < 8; ++i) o[i] = (f4){0.f, 0.f, 0.f, 0.f};
    float m_st[4], l_st[4];
#pragma unroll
    for (int r = 0; r < 4; ++r) { m_st[r] = -1e30f; l_st[r] = 0.f; }

    for (int kb = 0; kb < qbase + 64; kb += 64) {
        // ---- S = Q K^T (4 n-tiles of 16 keys) ----
        f4 s[4];
#pragma unroll
        for (int nt = 0; nt < 4; ++nt) s[nt] = (f4){0.f, 0.f, 0.f, 0.f};
        const _Float16* Kp = Kh + ((size_t)b * T_ + kb + col) * D_ + quad * 8;
#pragma unroll
        for (int nt = 0; nt < 4; ++nt)
#pragma unroll
            for (int ks = 0; ks < 4; ++ks) {
                const h8 bk = *(const h8*)(Kp + (size_t)nt * 16 * D_ + ks * 32);
                s[nt] = __builtin_amdgcn_mfma_f32_16x16x32_f16(qf[ks], bk, s[nt], 0, 0, 0);
            }

        // ---- scale + causal mask (D layout: row=quad*4+reg, col=lane&15) ----
#pragma unroll
        for (int nt = 0; nt < 4; ++nt) {
            const int key = kb + nt * 16 + col;
#pragma unroll
            for (int reg = 0; reg < 4; ++reg) {
                const int qr = qrow + quad * 4 + reg;
                const float sv = s[nt][reg] * SCALE;
                s[nt][reg] = (key <= qr) ? sv : -1e30f;
            }
        }

        // ---- online softmax (rows live in 16-lane groups within each quad) ----
        float mloc[4];
#pragma unroll
        for (int reg = 0; reg < 4; ++reg)
            mloc[reg] = fmaxf(fmaxf(s[0][reg], s[1][reg]), fmaxf(s[2][reg], s[3][reg]));
#pragma unroll
        for (int off = 1; off < 16; off <<= 1)
#pragma unroll
            for (int reg = 0; reg < 4; ++reg)
                mloc[reg] = fmaxf(mloc[reg], __shfl_xor(mloc[reg], off));

        float alpha[4];
#pragma unroll
        for (int reg = 0; reg < 4; ++reg) {
            const float mn = fmaxf(m_st[reg], mloc[reg]);
            alpha[reg] = __expf(m_st[reg] - mn);
            m_st[reg] = mn;
        }
        float rs[4] = {0.f, 0.f, 0.f, 0.f};
#pragma unroll
        for (int nt = 0; nt < 4; ++nt)
#pragma unroll
            for (int reg = 0; reg < 4; ++reg) {
                const float p = __expf(s[nt][reg] - m_st[reg]);
                s[nt][reg] = p;
                rs[reg] += p;
            }
#pragma unroll
        for (int off = 1; off < 16; off <<= 1)
#pragma unroll
            for (int reg = 0; reg < 4; ++reg)
                rs[reg] += __shfl_xor(rs[reg], off);
#pragma unroll
        for (int reg = 0; reg < 4; ++reg)
            l_st[reg] = l_st[reg] * alpha[reg] + rs[reg];

        // ---- rescale O ----
#pragma unroll
        for (int nt2 = 0; nt2 < 8; ++nt2)
#pragma unroll
            for (int reg = 0; reg < 4; ++reg)
                o[nt2][reg] *= alpha[reg];

        // ---- P: C-layout -> LDS -> A-layout ----
#pragma unroll
        for (int nt = 0; nt < 4; ++nt)
#pragma unroll
            for (int reg = 0; reg < 4; ++reg)
                Pl[w][quad * 4 + reg][nt * 16 + col] = (_Float16)s[nt][reg];
        __syncthreads();   // uniform trip count; also orders LDS write->read

        h8 pa[2];
#pragma unroll
        for (int ksP = 0; ksP < 2; ++ksP)
            pa[ksP] = *(const h8*)&Pl[w][col][ksP * 32 + quad * 8];

        // ---- O += P V (B-operand from Vt[d][j], row-contiguous) ----
        const _Float16* Vp = Vt + ((size_t)b * D_ + col) * T_ + kb + quad * 8;
#pragma unroll
        for (int nt2 = 0; nt2 < 8; ++nt2)
#pragma unroll
            for (int ksP = 0; ksP < 2; ++ksP) {
                const h8 bv2 = *(const h8*)(Vp + (size_t)nt2 * 16 * T_ + ksP * 32);
                o[nt2] = __builtin_amdgcn_mfma_f32_16x16x32_f16(pa[ksP], bv2, o[nt2], 0, 0, 0);
            }
        __syncthreads();   // protect Pl before next iteration's writes
    }

    // ---- finalize: out fp32 ----
#pragma unroll
    for (int nt2 = 0; nt2 < 8; ++nt2)
#pragma unroll
        for (int reg = 0; reg < 4; ++reg)
            out[((size_t)b * T_ + qrow + quad * 4 + reg) * D_ + nt2 * 16 + col] =
                o[nt2][reg] / l_st[reg];
}

extern "C" void kernel_launch(void* const* d_in, const int* in_sizes, int n_in,
                              void* d_out, int out_size, void* d_ws, size_t ws_size,
                              hipStream_t stream) {
    const float* x  = (const float*)d_in[0];
    const float* Wq = (const float*)d_in[1];
    const float* bq = (const float*)d_in[2];
    const float* Wk = (const float*)d_in[3];
    const float* bk = (const float*)d_in[4];
    const float* Wv = (const float*)d_in[5];
    const float* bv = (const float*)d_in[6];

    _Float16* Qh = (_Float16*)d_ws;                       // [B*T][D] f16, 4 MB
    _Float16* Kh = Qh + (size_t)B_ * T_ * D_;             // [B*T][D] f16, 4 MB
    _Float16* Vt = Kh + (size_t)B_ * T_ * D_;             // [B][D][T] f16, 4 MB

    qkv_mfma<<<dim3(B_ * T_ / 128, 3), dim3(256), 0, stream>>>(
        x, Wq, bq, Wk, bk, Wv, bv, Qh, Kh, Vt);

    flash_attn<<<dim3(T_ / 64, B_), dim3(256), 0, stream>>>(
        Qh, Kh, Vt, (float*)d_out);
}

// Round 12
// 295.121 us; speedup vs baseline: 4.1351x; 1.0879x over previous
//
#include <hip/hip_runtime.h>

#define B_ 8
#define T_ 2048
#define E_ 768
#define D_ 128
#define SCALE 0.08838834764831845f   // 1/sqrt(128)

typedef _Float16 h8 __attribute__((ext_vector_type(8)));
typedef _Float16 h4 __attribute__((ext_vector_type(4)));
typedef float f4 __attribute__((ext_vector_type(4)));

// =============== Kernel 1: fused QKV projection (x read once) ===============
// grid = 256 (one 64-row m-tile per block), block = 256 (4 waves).
// Each wave owns a 96-col slice of the 384-wide (Q|K|V) output.
__global__ __launch_bounds__(256) void qkv_fused(
    const float* __restrict__ x,
    const float* __restrict__ Wq, const float* __restrict__ bq,
    const float* __restrict__ Wk, const float* __restrict__ bk,
    const float* __restrict__ Wv, const float* __restrict__ bv,
    _Float16* __restrict__ Qh, _Float16* __restrict__ Kh,
    _Float16* __restrict__ Vt)
{
    __shared__ _Float16 As[64 * 64];        // 8 KB  x-tile, XOR-swizzled
    __shared__ _Float16 Bs[3 * 128 * 64];   // 48 KB W-tiles [y][n][k], swizzled

    const int t = threadIdx.x;
    const int lane = t & 63, w = t >> 6;
    const int quad = lane >> 4, col = lane & 15;
    const int m0 = blockIdx.x * 64;

    const float* Wp[3] = {Wq, Wk, Wv};

    f4 acc[4][6];
#pragma unroll
    for (int mt = 0; mt < 4; ++mt)
#pragma unroll
        for (int nt = 0; nt < 6; ++nt) acc[mt][nt] = (f4){0.f, 0.f, 0.f, 0.f};

    for (int kb = 0; kb < E_; kb += 64) {
        // ---- stage x tile: 64x64 fp32 -> f16 swizzled ----
        {
            const int r = t >> 2, cb = (t & 3) * 16;
            const float* xr = &x[(size_t)(m0 + r) * E_ + kb + cb];
#pragma unroll
            for (int i = 0; i < 4; ++i) {
                const float4 v = *(const float4*)(xr + 4 * i);
                h4 hv; hv[0] = (_Float16)v.x; hv[1] = (_Float16)v.y;
                hv[2] = (_Float16)v.z; hv[3] = (_Float16)v.w;
                const int kk4 = cb + 4 * i;
                *(h4*)&As[r * 64 + (((kk4 >> 3) ^ (r & 7)) << 3) + (kk4 & 7)] = hv;
            }
        }
        // ---- stage 3 W tiles transposed: Bs[y][n][k] swizzled ----
        {
            const int n4 = (t & 31) * 4, kk0 = t >> 5;
#pragma unroll
            for (int y = 0; y < 3; ++y) {
                const float* W = Wp[y];
                _Float16* By = &Bs[y * 8192];
#pragma unroll
                for (int i = 0; i < 8; ++i) {
                    const int kk = kk0 + 8 * i;
                    const float4 v = *(const float4*)&W[(size_t)(kb + kk) * D_ + n4];
                    const int ck = kk >> 3, ko = kk & 7;
                    By[(n4 + 0) * 64 + ((ck ^ ((n4 + 0) & 7)) << 3) + ko] = (_Float16)v.x;
                    By[(n4 + 1) * 64 + ((ck ^ ((n4 + 1) & 7)) << 3) + ko] = (_Float16)v.y;
                    By[(n4 + 2) * 64 + ((ck ^ ((n4 + 2) & 7)) << 3) + ko] = (_Float16)v.z;
                    By[(n4 + 3) * 64 + ((ck ^ ((n4 + 3) & 7)) << 3) + ko] = (_Float16)v.w;
                }
            }
        }
        __syncthreads();

#pragma unroll
        for (int ks = 0; ks < 2; ++ks) {
            const int sc = ((ks << 2) + quad) ^ (col & 7);
            h8 a[4], bf[6];
#pragma unroll
            for (int mt = 0; mt < 4; ++mt)
                a[mt] = *(const h8*)&As[(mt * 16 + col) * 64 + (sc << 3)];
#pragma unroll
            for (int nt = 0; nt < 6; ++nt) {
                const int n16 = w * 96 + nt * 16;
                const int y = n16 >> 7, nl = n16 & 127;
                bf[nt] = *(const h8*)&Bs[y * 8192 + (nl + col) * 64 + (sc << 3)];
            }
#pragma unroll
            for (int mt = 0; mt < 4; ++mt)
#pragma unroll
                for (int nt = 0; nt < 6; ++nt)
                    acc[mt][nt] = __builtin_amdgcn_mfma_f32_16x16x32_f16(
                        a[mt], bf[nt], acc[mt][nt], 0, 0, 0);
        }
        __syncthreads();
    }

    // ---- epilogue: bias add into LDS (reuse Bs as Cs[64][384]), then coalesced out ----
    const float* bp[3] = {bq, bk, bv};
    _Float16* Cs = Bs;
#pragma unroll
    for (int nt = 0; nt < 6; ++nt) {
        const int n16 = w * 96 + nt * 16;
        const int y = n16 >> 7, nl = n16 & 127;
        const float bb = bp[y][nl + col];
#pragma unroll
        for (int mt = 0; mt < 4; ++mt)
#pragma unroll
            for (int reg = 0; reg < 4; ++reg) {
                const int m = mt * 16 + quad * 4 + reg;
                Cs[m * 384 + n16 + col] = (_Float16)(acc[mt][nt][reg] + bb);
            }
    }
    __syncthreads();

    // Q/K rows: coalesced h8 stores
    {
        const int m = t >> 2, seg = t & 3;
#pragma unroll
        for (int j = 0; j < 8; ++j) {
            const int n = seg * 64 + j * 8;
            const h8 v = *(const h8*)&Cs[m * 384 + n];
            if (n < 128) *(h8*)&Qh[(size_t)(m0 + m) * D_ + n] = v;
            else         *(h8*)&Kh[(size_t)(m0 + m) * D_ + (n - 128)] = v;
        }
    }
    // V transposed: gather columns from LDS, coalesced h8 stores
    {
        const int vn = t & 127, part = t >> 7;
        const int bidx = m0 >> 11, tt0 = m0 & 2047;
#pragma unroll
        for (int j = 0; j < 4; ++j) {
            const int ms = part * 32 + j * 8;
            h8 hv;
#pragma unroll
            for (int e = 0; e < 8; ++e) hv[e] = Cs[(ms + e) * 384 + 256 + vn];
            *(h8*)&Vt[((size_t)bidx * D_ + vn) * T_ + tt0 + ms] = hv;
        }
    }
}

// =============== Kernel 2: flash attention, register-pipelined ===============
// grid = (B, T/64) — batch-major so same-batch blocks share an XCD's L2.
// 4 waves x 16 q-rows; K-tiles of 64; ping-pong K/V register buffers.
__global__ __launch_bounds__(256, 1) void flash_attn(
    const _Float16* __restrict__ Qh,
    const _Float16* __restrict__ Kh,
    const _Float16* __restrict__ Vt,
    float* __restrict__ out)
{
    __shared__ _Float16 Pl[4][16][72];   // per-wave P scratch (no barriers needed)

    const int t = threadIdx.x, lane = t & 63, w = t >> 6;
    const int quad = lane >> 4, col = lane & 15;
    const int b = blockIdx.x;
    const int qbase = blockIdx.y * 64;
    const int qrow = qbase + w * 16;

    h8 qf[4];
    const _Float16* Qp = Qh + ((size_t)b * T_ + qrow + col) * D_ + quad * 8;
#pragma unroll
    for (int ks = 0; ks < 4; ++ks) qf[ks] = *(const h8*)(Qp + ks * 32);

    f4 o[8];
#pragma unroll
    for (int i = 0; i < 8; ++i) o[i] = (f4){0.f, 0.f, 0.f, 0.f};
    float m_st[4], l_st[4];
#pragma unroll
    for (int r = 0; r < 4; ++r) { m_st[r] = -1e30f; l_st[r] = 0.f; }

    const _Float16* KB = Kh + ((size_t)b * T_ + col) * D_ + quad * 8;
    const _Float16* VB = Vt + ((size_t)b * D_ + col) * T_ + quad * 8;

#define LOADK(dst, kbase)                                                  \
    _Pragma("unroll")                                                      \
    for (int nt = 0; nt < 4; ++nt)                                         \
    _Pragma("unroll")                                                      \
    for (int ks = 0; ks < 4; ++ks)                                         \
        dst[nt * 4 + ks] = *(const h8*)(KB + (size_t)((kbase) + nt * 16) * D_ + ks * 32);

#define LOADV(dst, kbase)                                                  \
    _Pragma("unroll")                                                      \
    for (int n2 = 0; n2 < 8; ++n2)                                         \
    _Pragma("unroll")                                                      \
    for (int kp = 0; kp < 2; ++kp)                                         \
        dst[n2 * 2 + kp] = *(const h8*)(VB + (size_t)(n2 * 16) * T_ + (kbase) + kp * 32);

    auto step = [&](const h8 (&kf)[16], const h8 (&vf)[16], const int kb,
                    const bool mask) __attribute__((always_inline)) {
        f4 s[4];
#pragma unroll
        for (int nt = 0; nt < 4; ++nt) s[nt] = (f4){0.f, 0.f, 0.f, 0.f};
#pragma unroll
        for (int nt = 0; nt < 4; ++nt)
#pragma unroll
            for (int ks = 0; ks < 4; ++ks)
                s[nt] = __builtin_amdgcn_mfma_f32_16x16x32_f16(qf[ks], kf[nt * 4 + ks], s[nt], 0, 0, 0);

        if (mask) {
#pragma unroll
            for (int nt = 0; nt < 4; ++nt) {
                const int key = kb + nt * 16 + col;
#pragma unroll
                for (int reg = 0; reg < 4; ++reg) {
                    const int qr = qrow + quad * 4 + reg;
                    const float sv = s[nt][reg] * SCALE;
                    s[nt][reg] = (key <= qr) ? sv : -1e30f;
                }
            }
        } else {
#pragma unroll
            for (int nt = 0; nt < 4; ++nt)
#pragma unroll
                for (int reg = 0; reg < 4; ++reg) s[nt][reg] *= SCALE;
        }

        float mloc[4];
#pragma unroll
        for (int reg = 0; reg < 4; ++reg)
            mloc[reg] = fmaxf(fmaxf(s[0][reg], s[1][reg]), fmaxf(s[2][reg], s[3][reg]));
#pragma unroll
        for (int off = 1; off < 16; off <<= 1)
#pragma unroll
            for (int reg = 0; reg < 4; ++reg)
                mloc[reg] = fmaxf(mloc[reg], __shfl_xor(mloc[reg], off));

        float alpha[4];
#pragma unroll
        for (int reg = 0; reg < 4; ++reg) {
            const float mn = fmaxf(m_st[reg], mloc[reg]);
            alpha[reg] = __expf(m_st[reg] - mn);
            m_st[reg] = mn;
        }
        float rs[4] = {0.f, 0.f, 0.f, 0.f};
#pragma unroll
        for (int nt = 0; nt < 4; ++nt)
#pragma unroll
            for (int reg = 0; reg < 4; ++reg) {
                const float p = __expf(s[nt][reg] - m_st[reg]);
                s[nt][reg] = p;
                rs[reg] += p;
            }
#pragma unroll
        for (int off = 1; off < 16; off <<= 1)
#pragma unroll
            for (int reg = 0; reg < 4; ++reg) rs[reg] += __shfl_xor(rs[reg], off);
#pragma unroll
        for (int reg = 0; reg < 4; ++reg) l_st[reg] = l_st[reg] * alpha[reg] + rs[reg];

#pragma unroll
        for (int n2 = 0; n2 < 8; ++n2)
#pragma unroll
            for (int reg = 0; reg < 4; ++reg) o[n2][reg] *= alpha[reg];

#pragma unroll
        for (int nt = 0; nt < 4; ++nt)
#pragma unroll
            for (int reg = 0; reg < 4; ++reg)
                Pl[w][quad * 4 + reg][nt * 16 + col] = (_Float16)s[nt][reg];
        const h8 pa0 = *(const h8*)&Pl[w][col][quad * 8];
        const h8 pa1 = *(const h8*)&Pl[w][col][32 + quad * 8];

#pragma unroll
        for (int n2 = 0; n2 < 8; ++n2) {
            o[n2] = __builtin_amdgcn_mfma_f32_16x16x32_f16(pa0, vf[n2 * 2 + 0], o[n2], 0, 0, 0);
            o[n2] = __builtin_amdgcn_mfma_f32_16x16x32_f16(pa1, vf[n2 * 2 + 1], o[n2], 0, 0, 0);
        }
    };

    const int ntiles = (qbase >> 6) + 1;
    h8 K0[16], V0[16], K1[16], V1[16];
    LOADK(K0, 0); LOADV(V0, 0);
    int ti = 0;
    while (true) {
        if (ti + 1 < ntiles) { LOADK(K1, ((ti + 1) << 6)); LOADV(V1, ((ti + 1) << 6)); }
        step(K0, V0, ti << 6, ti + 1 == ntiles);
        if (++ti == ntiles) break;
        if (ti + 1 < ntiles) { LOADK(K0, ((ti + 1) << 6)); LOADV(V0, ((ti + 1) << 6)); }
        step(K1, V1, ti << 6, ti + 1 == ntiles);
        if (++ti == ntiles) break;
    }

#pragma unroll
    for (int n2 = 0; n2 < 8; ++n2)
#pragma unroll
        for (int reg = 0; reg < 4; ++reg)
            out[((size_t)b * T_ + qrow + quad * 4 + reg) * D_ + n2 * 16 + col] =
                o[n2][reg] / l_st[reg];
#undef LOADK
#undef LOADV
}

extern "C" void kernel_launch(void* const* d_in, const int* in_sizes, int n_in,
                              void* d_out, int out_size, void* d_ws, size_t ws_size,
                              hipStream_t stream) {
    const float* x  = (const float*)d_in[0];
    const float* Wq = (const float*)d_in[1];
    const float* bq = (const float*)d_in[2];
    const float* Wk = (const float*)d_in[3];
    const float* bk = (const float*)d_in[4];
    const float* Wv = (const float*)d_in[5];
    const float* bv = (const float*)d_in[6];

    _Float16* Qh = (_Float16*)d_ws;                       // [B*T][D] f16
    _Float16* Kh = Qh + (size_t)B_ * T_ * D_;             // [B*T][D] f16
    _Float16* Vt = Kh + (size_t)B_ * T_ * D_;             // [B][D][T] f16

    qkv_fused<<<dim3(B_ * T_ / 64), dim3(256), 0, stream>>>(
        x, Wq, bq, Wk, bk, Wv, bv, Qh, Kh, Vt);

    flash_attn<<<dim3(B_, T_ / 64), dim3(256), 0, stream>>>(
        Qh, Kh, Vt, (float*)d_out);
}